// Round 5
// baseline (924.288 us; speedup 1.0000x reference)
//
#include <hip/hip_runtime.h>
#include <hip/hip_bf16.h>

#define DHW (16 * 16 * 30)   // 7680 voxels per channel
#define NWCOL 7680           // hw columns = 120 f * 64 c
#define KTOT 30720           // hw rows
#define KSPLIT 240
#define KCH (KTOT / KSPLIT)  // 128
#define NBLK (15 * KSPLIT)   // 3600 K2 blocks
// ln(1024)/39
#define LN1024_OVER_39 0.17773004629742187f

// ---------------------------------------------------------------------------
// K1: conv chain at strided voxels only. One block per (b, zi, yi); 15 w's.
// Writes fvecT[k][b], k = ((ch*8+zi)*8+yi)*15 + w   (torch flatten order)
// ---------------------------------------------------------------------------
__global__ __launch_bounds__(256) void k1_conv(
    const float* __restrict__ feat0,
    const float* __restrict__ cw1, const float* __restrict__ cb1,
    const float* __restrict__ cw2, const float* __restrict__ cb2,
    const float* __restrict__ cw3, const float* __restrict__ cb3,
    float* __restrict__ fvecT)
{
    const int yi = blockIdx.x;   // 0..7
    const int zi = blockIdx.y;   // 0..7
    const int b  = blockIdx.z;   // 0..7
    const int t  = threadIdx.x;  // 0..255

    __shared__ float sIn[256][16];
    __shared__ float sH1[128][16];
    __shared__ float sH2[64][16];

    // ---- load input voxels: feat0[b, c, 2zi, 2yi, 2w], w = 0..14 ----
    {
        const int w  = t & 15;
        const int cg = t >> 4;  // 0..15
        const float* base = feat0 + (size_t)b * 256 * DHW
                            + (2 * zi) * (16 * 30) + (2 * yi) * 30 + 2 * w;
        for (int c0 = 0; c0 < 256; c0 += 16) {
            const int c = c0 + cg;
            sIn[c][w] = (w < 15) ? base[(size_t)c * DHW] : 0.f;
        }
    }
    __syncthreads();

    // ---- conv1: 256 -> 128, relu.  thread: o = t&127, half = t>>7 ----
    {
        const int o = t & 127, half = t >> 7;
        const int w0 = half * 8;
        float acc[8];
        #pragma unroll
        for (int i = 0; i < 8; ++i) acc[i] = cb1[o];
        for (int c = 0; c < 256; ++c) {
            const float wv = cw1[c * 128 + o];
            #pragma unroll
            for (int i = 0; i < 8; ++i) acc[i] += sIn[c][w0 + i] * wv;
        }
        #pragma unroll
        for (int i = 0; i < 8; ++i) sH1[o][w0 + i] = fmaxf(acc[i], 0.f);
    }
    __syncthreads();

    // ---- conv2: 128 -> 64, relu.  thread: o = t&63, q = t>>6 (w quad) ----
    {
        const int o = t & 63, q = t >> 6;
        const int w0 = q * 4;
        float acc[4];
        #pragma unroll
        for (int i = 0; i < 4; ++i) acc[i] = cb2[o];
        for (int c = 0; c < 128; ++c) {
            const float wv = cw2[c * 64 + o];
            #pragma unroll
            for (int i = 0; i < 4; ++i) acc[i] += sH1[c][w0 + i] * wv;
        }
        #pragma unroll
        for (int i = 0; i < 4; ++i) sH2[o][w0 + i] = fmaxf(acc[i], 0.f);
    }
    __syncthreads();

    // ---- conv3: 64 -> 32, relu, scatter to fvecT.  o = t&31, q = t>>5 ----
    {
        const int o = t & 31, q = t >> 5;  // q = 0..7
        const int w0 = q * 2;
        float acc[2];
        #pragma unroll
        for (int i = 0; i < 2; ++i) acc[i] = cb3[o];
        for (int c = 0; c < 64; ++c) {
            const float wv = cw3[c * 32 + o];
            #pragma unroll
            for (int i = 0; i < 2; ++i) acc[i] += sH2[c][w0 + i] * wv;
        }
        #pragma unroll
        for (int i = 0; i < 2; ++i) {
            const int w = w0 + i;
            if (w < 15) {
                const int k = ((o * 8 + zi) * 8 + yi) * 15 + w;
                fvecT[(size_t)k * 8 + b] = fmaxf(acc[i], 0.f);
            }
        }
    }
}

// ---------------------------------------------------------------------------
// K2 (R2-best variant, unchanged): column-panel streamer.
// grid = (15 column groups of 512 cols, KSPLIT k-chunks), 128 threads.
// NOTE: launched 4x this round as a timing probe — K2 is a pure function of
// (hw, fvecT, coord) and rewrites `partial` identically, so replicas are
// deterministic and output-invariant.
// ---------------------------------------------------------------------------
__global__ __launch_bounds__(128) void k2_stream(
    const float* __restrict__ hw,
    const float* __restrict__ fvecT,
    const float* __restrict__ coord,
    float* __restrict__ partial)
{
    __shared__ float zpart[512];
    __shared__ float sF[KCH * 8];  // this k-chunk's fvec, all 8 batches (4 KB)
    const int t = threadIdx.x;
    const int kbase = blockIdx.y * KCH;

    #pragma unroll
    for (int r = 0; r < 4; ++r) zpart[t * 4 + r] = 0.f;
    #pragma unroll
    for (int i = 0; i < 8; ++i)
        sF[t + 128 * i] = fvecT[(size_t)kbase * 8 + t + 128 * i];
    __syncthreads();

    const int lane = t & 63;
    const int jw = blockIdx.x * 512 + (t >> 6) * 256;  // wave's 256-col strip
    const int j0 = jw + 4 * lane;                      // this lane's 4 cols

    float acc[8][4] = {};
    const float* hp = hw + (size_t)kbase * NWCOL + j0;

    #pragma unroll 4
    for (int kk = 0; kk < KCH; ++kk) {
        const float4 h = *(const float4*)hp;
        hp += NWCOL;
        const float4 f0 = *(const float4*)&sF[kk * 8];      // broadcast
        const float4 f1 = *(const float4*)&sF[kk * 8 + 4];  // broadcast
        const float fv[8] = {f0.x, f0.y, f0.z, f0.w, f1.x, f1.y, f1.z, f1.w};
        #pragma unroll
        for (int b = 0; b < 8; ++b) {
            acc[b][0] += fv[b] * h.x;
            acc[b][1] += fv[b] * h.y;
            acc[b][2] += fv[b] * h.z;
            acc[b][3] += fv[b] * h.w;
        }
    }

    // fold z[b, f] for this lane's f; accumulate into LDS z1 partial
    const int f = j0 >> 6;           // 0..119, constant over the 4 cols
    const int i3 = f / 40;           // coord dim
    const int q = f - i3 * 40;       // freq index
    const float freqv = __expf((float)q * LN1024_OVER_39);
    const int cb = 4 * (lane & 15);  // column (mod 64) of element e=0

    #pragma unroll
    for (int b = 0; b < 8; ++b) {
        const float zv = coord[b * 3 + i3] * freqv;
        #pragma unroll
        for (int e = 0; e < 4; ++e)
            atomicAdd(&zpart[b * 64 + cb + e], zv * acc[b][e]);
    }
    __syncthreads();

    // coalesced partial write: partial[bid][512]
    const int bid = blockIdx.x + 15 * blockIdx.y;
    float4* pp = (float4*)(partial + (size_t)bid * 512);
    pp[t] = *(const float4*)&zpart[t * 4];
}

// ---------------------------------------------------------------------------
// K2b: reduce partial[3600][512] -> z1[512]. 64 blocks x 256 threads.
// ---------------------------------------------------------------------------
__global__ __launch_bounds__(256) void k2b_reduce(
    const float* __restrict__ partial, float* __restrict__ z1)
{
    __shared__ float s[256];
    const int t = threadIdx.x;
    const int o = blockIdx.x * 8 + (t & 7);  // output element
    float sum = 0.f;
    for (int blk = t >> 3; blk < NBLK; blk += 32)
        sum += partial[(size_t)blk * 512 + o];
    s[t] = sum;
    __syncthreads();
    if (t < 8) {
        float tot = 0.f;
        #pragma unroll
        for (int i = 0; i < 32; ++i) tot += s[t + 8 * i];
        z1[blockIdx.x * 8 + t] = tot;
    }
}

// ---------------------------------------------------------------------------
// K3: hb-bias term + 3-layer MLP tail. One block, 512 threads = (b=8, c=64).
// ---------------------------------------------------------------------------
__global__ __launch_bounds__(512) void k3_tail(
    const float* __restrict__ z1acc, const float* __restrict__ coord,
    const float* __restrict__ hb,
    const float* __restrict__ w1, const float* __restrict__ b1,
    const float* __restrict__ w2, const float* __restrict__ b2,
    const float* __restrict__ wo, const float* __restrict__ bo,
    float* __restrict__ out)
{
    __shared__ float sz[8][64];
    __shared__ float s2[8][64];
    __shared__ float sfreq[40];
    __shared__ float sc[24];
    const int t = threadIdx.x;
    if (t < 40) sfreq[t] = __expf((float)t * LN1024_OVER_39);
    if (t < 24) sc[t] = coord[t];
    __syncthreads();

    const int b = t >> 6, c = t & 63;

    // z1[b][c] = z1acc + sum_f z[b,f] * hb[f*64+c]
    float a = z1acc[t];
    #pragma unroll
    for (int i = 0; i < 3; ++i) {
        const float cv = sc[b * 3 + i];
        #pragma unroll 8
        for (int q = 0; q < 40; ++q)
            a += cv * sfreq[q] * hb[(i * 40 + q) * 64 + c];
    }
    sz[b][c] = a;  // no activation on modulated layer 0
    __syncthreads();

    float a1 = b1[c];
    #pragma unroll 8
    for (int cc = 0; cc < 64; ++cc) a1 += sz[b][cc] * w1[cc * 64 + c];
    s2[b][c] = fmaxf(a1, 0.f);
    __syncthreads();

    float a2 = b2[c];
    #pragma unroll 8
    for (int cc = 0; cc < 64; ++cc) a2 += s2[b][cc] * w2[cc * 64 + c];
    sz[b][c] = fmaxf(a2, 0.f);
    __syncthreads();

    if (t < 24) {
        const int bb = t / 3, i = t - bb * 3;
        float o = bo[i];
        #pragma unroll 8
        for (int cc = 0; cc < 64; ++cc) o += sz[bb][cc] * wo[cc * 3 + i];
        out[t] = o;
    }
}

// ---------------------------------------------------------------------------
extern "C" void kernel_launch(void* const* d_in, const int* in_sizes, int n_in,
                              void* d_out, int out_size, void* d_ws, size_t ws_size,
                              hipStream_t stream)
{
    const float* coord = (const float*)d_in[0];
    const float* feat0 = (const float*)d_in[1];
    const float* cw1 = (const float*)d_in[2];
    const float* cb1 = (const float*)d_in[3];
    const float* cw2 = (const float*)d_in[4];
    const float* cb2 = (const float*)d_in[5];
    const float* cw3 = (const float*)d_in[6];
    const float* cb3 = (const float*)d_in[7];
    const float* hw  = (const float*)d_in[8];
    const float* hb  = (const float*)d_in[9];
    const float* w1  = (const float*)d_in[10];
    const float* b1  = (const float*)d_in[11];
    const float* w2  = (const float*)d_in[12];
    const float* b2  = (const float*)d_in[13];
    const float* wo  = (const float*)d_in[14];
    const float* bo  = (const float*)d_in[15];
    float* out = (float*)d_out;

    float* fvecT   = (float*)d_ws;                  // 30720*8 floats = 983 KB
    float* partial = fvecT + (size_t)KTOT * 8;      // 3600*512 floats = 7.37 MB
    float* z1      = partial + (size_t)NBLK * 512;  // 512 floats

    k1_conv<<<dim3(8, 8, 8), 256, 0, stream>>>(feat0, cw1, cb1, cw2, cb2,
                                               cw3, cb3, fvecT);
    // --- timing probe: K2 x4 (idempotent). K2 = (T4 - T1)/3, eps-free. ---
    k2_stream<<<dim3(15, KSPLIT), 128, 0, stream>>>(hw, fvecT, coord, partial);
    k2_stream<<<dim3(15, KSPLIT), 128, 0, stream>>>(hw, fvecT, coord, partial);
    k2_stream<<<dim3(15, KSPLIT), 128, 0, stream>>>(hw, fvecT, coord, partial);
    k2_stream<<<dim3(15, KSPLIT), 128, 0, stream>>>(hw, fvecT, coord, partial);
    k2b_reduce<<<64, 256, 0, stream>>>(partial, z1);
    k3_tail<<<1, 512, 0, stream>>>(z1, coord, hb, w1, b1, w2, b2, wo, bo, out);
}

// Round 6
// 274.011 us; speedup vs baseline: 3.3732x; 3.3732x over previous
//
#include <hip/hip_runtime.h>
#include <hip/hip_bf16.h>

#define DHW (16 * 16 * 30)   // 7680 voxels per channel
#define NWCOL 7680           // hw columns = 120 f * 64 c
#define KTOT 30720           // hw rows
#define KSPLIT 240
#define KCH (KTOT / KSPLIT)  // 128
#define NBLK (15 * KSPLIT)   // 3600 K2 blocks
// ln(1024)/39
#define LN1024_OVER_39 0.17773004629742187f

// ---------------------------------------------------------------------------
// K1: conv chain at strided voxels. One 512-thread block per (b, zi, yi).
// All weights staged in LDS (coalesced float4) -> inner loops are pure
// LDS-broadcast + FMA. 60 KB LDS -> 2 blocks/CU, 16 waves/CU.
// Writes fvecT[k][b], k = ((ch*8+zi)*8+yi)*15 + w   (torch flatten order)
// ---------------------------------------------------------------------------
__global__ __launch_bounds__(512) void k1_conv(
    const float* __restrict__ feat0,
    const float* __restrict__ cw1, const float* __restrict__ cb1,
    const float* __restrict__ cw2, const float* __restrict__ cb2,
    const float* __restrict__ cw3, const float* __restrict__ cb3,
    float* __restrict__ fvecT)
{
    const int yi = blockIdx.x;   // 0..7
    const int zi = blockIdx.y;   // 0..7
    const int b  = blockIdx.z;   // 0..7
    const int t  = threadIdx.x;  // 0..511

    __shared__ float sIn[256][16];  // 16 KB
    __shared__ float sW[8192];      // 32 KB staging (cw1 tiles / cw2 / cw3)
    __shared__ float sH1[128][16];  // 8 KB
    __shared__ float sH2[64][16];   // 4 KB

    // ---- load input voxels: feat0[b, c, 2zi, 2yi, 2w], w = 0..14 ----
    {
        const int w  = t & 15;
        const int cg = t >> 4;  // 0..31
        const float* base = feat0 + (size_t)b * 256 * DHW
                            + (2 * zi) * (16 * 30) + (2 * yi) * 30 + 2 * w;
        #pragma unroll
        for (int c0 = 0; c0 < 256; c0 += 32) {
            const int c = c0 + cg;
            sIn[c][w] = (w < 15) ? base[(size_t)c * DHW] : 0.f;
        }
    }

    // ---- conv1: 256 -> 128, relu.  o = t&127, wq = t>>7 (4 w's each) ----
    {
        const int o = t & 127, wq = t >> 7;
        const int w0 = 4 * wq;
        float acc[4];
        const float bv = cb1[o];
        #pragma unroll
        for (int i = 0; i < 4; ++i) acc[i] = bv;

        for (int c0 = 0; c0 < 256; c0 += 64) {
            // stage 64x128 tile of cw1 (contiguous 8192 floats)
            const float4* src = (const float4*)(cw1 + c0 * 128);
            float4* dst = (float4*)sW;
            #pragma unroll
            for (int p = 0; p < 4; ++p) dst[t + 512 * p] = src[t + 512 * p];
            __syncthreads();
            #pragma unroll 8
            for (int cc = 0; cc < 64; ++cc) {
                const float wv = sW[cc * 128 + o];
                const float4 xi = *(const float4*)&sIn[c0 + cc][w0];
                acc[0] += xi.x * wv;
                acc[1] += xi.y * wv;
                acc[2] += xi.z * wv;
                acc[3] += xi.w * wv;
            }
            __syncthreads();
        }
        #pragma unroll
        for (int i = 0; i < 4; ++i) sH1[o][w0 + i] = fmaxf(acc[i], 0.f);
    }
    __syncthreads();

    // ---- conv2: 128 -> 64, relu.  o = t&63, q = t>>6 (2 w's each) ----
    {
        // stage cw2 fully: 128x64 = 8192 floats
        const float4* src = (const float4*)cw2;
        float4* dst = (float4*)sW;
        #pragma unroll
        for (int p = 0; p < 4; ++p) dst[t + 512 * p] = src[t + 512 * p];
        __syncthreads();

        const int o = t & 63, q = t >> 6;
        const int w0 = 2 * q;
        float acc[2];
        const float bv = cb2[o];
        acc[0] = bv; acc[1] = bv;
        #pragma unroll 8
        for (int cc = 0; cc < 128; ++cc) {
            const float wv = sW[cc * 64 + o];
            const float2 xi = *(const float2*)&sH1[cc][w0];
            acc[0] += xi.x * wv;
            acc[1] += xi.y * wv;
        }
        sH2[o][w0]     = fmaxf(acc[0], 0.f);
        sH2[o][w0 + 1] = fmaxf(acc[1], 0.f);
    }
    __syncthreads();

    // ---- conv3: 64 -> 32, relu, scatter.  o = t&31, w = t>>5 (16, 15 used) --
    {
        // stage cw3: 64x32 = 2048 floats
        ((float4*)sW)[t] = ((const float4*)cw3)[t];
        __syncthreads();

        const int o = t & 31, w = t >> 5;
        float acc = cb3[o];
        #pragma unroll 8
        for (int cc = 0; cc < 64; ++cc)
            acc += sH2[cc][w] * sW[cc * 32 + o];
        if (w < 15) {
            const int k = ((o * 8 + zi) * 8 + yi) * 15 + w;
            fvecT[(size_t)k * 8 + b] = fmaxf(acc, 0.f);
        }
    }
}

// ---------------------------------------------------------------------------
// K2: column-panel streamer (R2 geometry), 64-thread blocks; each lane owns
// col-quads at +0 and +256 of the block's 512-col strip -> 2 coalesced 1 KB
// loads + 64 FMA per k, 8 KB in flight per wave at unroll 4.
// grid = (15 column strips, KSPLIT k-chunks).
// ---------------------------------------------------------------------------
__global__ __launch_bounds__(64) void k2_stream(
    const float* __restrict__ hw,
    const float* __restrict__ fvecT,
    const float* __restrict__ coord,
    float* __restrict__ partial)
{
    __shared__ float zpart[512];
    __shared__ float sF[KCH * 8];  // this k-chunk's fvec, all 8 batches (4 KB)
    const int t = threadIdx.x;     // 0..63
    const int kbase = blockIdx.y * KCH;

    #pragma unroll
    for (int r = 0; r < 8; ++r) zpart[t * 8 + r] = 0.f;
    {
        const float4* fsrc = (const float4*)(fvecT + (size_t)kbase * 8);
        float4* fdst = (float4*)sF;
        #pragma unroll
        for (int p = 0; p < 4; ++p) fdst[t + 64 * p] = fsrc[t + 64 * p];
    }
    __syncthreads();

    const int jw = blockIdx.x * 512;
    const int j0 = jw + 4 * t;

    float accA[8][4] = {}, accB[8][4] = {};
    const float* hp = hw + (size_t)kbase * NWCOL + j0;

    #pragma unroll 4
    for (int kk = 0; kk < KCH; ++kk) {
        const float4 hA = *(const float4*)hp;
        const float4 hB = *(const float4*)(hp + 256);
        hp += NWCOL;
        const float4 f0 = *(const float4*)&sF[kk * 8];      // broadcast
        const float4 f1 = *(const float4*)&sF[kk * 8 + 4];  // broadcast
        const float fv[8] = {f0.x, f0.y, f0.z, f0.w, f1.x, f1.y, f1.z, f1.w};
        #pragma unroll
        for (int b = 0; b < 8; ++b) {
            accA[b][0] += fv[b] * hA.x;
            accA[b][1] += fv[b] * hA.y;
            accA[b][2] += fv[b] * hA.z;
            accA[b][3] += fv[b] * hA.w;
            accB[b][0] += fv[b] * hB.x;
            accB[b][1] += fv[b] * hB.y;
            accB[b][2] += fv[b] * hB.z;
            accB[b][3] += fv[b] * hB.w;
        }
    }

    // fold z[b,f] for both col-quads (same output cols cq.., different f)
    const int fA = 8 * blockIdx.x + (t >> 4);
    const int fB = fA + 4;
    const int i3A = fA / 40, qA = fA - 40 * i3A;
    const int i3B = fB / 40, qB = fB - 40 * i3B;
    const float freqA = __expf((float)qA * LN1024_OVER_39);
    const float freqB = __expf((float)qB * LN1024_OVER_39);
    const int cq = 4 * (t & 15);

    #pragma unroll
    for (int b = 0; b < 8; ++b) {
        const float zvA = coord[b * 3 + i3A] * freqA;
        const float zvB = coord[b * 3 + i3B] * freqB;
        #pragma unroll
        for (int e = 0; e < 4; ++e)
            atomicAdd(&zpart[b * 64 + cq + e],
                      zvA * accA[b][e] + zvB * accB[b][e]);
    }
    __syncthreads();

    const int bid = blockIdx.x + 15 * blockIdx.y;
    float4* pp = (float4*)(partial + (size_t)bid * 512);
    pp[t]      = ((const float4*)zpart)[t];
    pp[t + 64] = ((const float4*)zpart)[t + 64];
}

// ---------------------------------------------------------------------------
// K2b: reduce partial[3600][512] -> z1[512]. 64 blocks x 256 threads.
// ---------------------------------------------------------------------------
__global__ __launch_bounds__(256) void k2b_reduce(
    const float* __restrict__ partial, float* __restrict__ z1)
{
    __shared__ float s[256];
    const int t = threadIdx.x;
    const int o = blockIdx.x * 8 + (t & 7);  // output element
    float sum = 0.f;
    for (int blk = t >> 3; blk < NBLK; blk += 32)
        sum += partial[(size_t)blk * 512 + o];
    s[t] = sum;
    __syncthreads();
    if (t < 8) {
        float tot = 0.f;
        #pragma unroll
        for (int i = 0; i < 32; ++i) tot += s[t + 8 * i];
        z1[blockIdx.x * 8 + t] = tot;
    }
}

// ---------------------------------------------------------------------------
// K3: hb-bias term + MLP tail, all weights LDS-staged (coalesced float4).
// One block, 512 threads = (b=8, c=64).
// ---------------------------------------------------------------------------
__global__ __launch_bounds__(512) void k3_tail(
    const float* __restrict__ z1acc, const float* __restrict__ coord,
    const float* __restrict__ hb,
    const float* __restrict__ w1, const float* __restrict__ b1,
    const float* __restrict__ w2, const float* __restrict__ b2,
    const float* __restrict__ wo, const float* __restrict__ bo,
    float* __restrict__ out)
{
    __shared__ float shb[7680];  // 30 KB
    __shared__ float sw1[4096];  // 16 KB
    __shared__ float sw2[4096];  // 16 KB
    __shared__ float swo[192];
    __shared__ float sz[8][64];
    __shared__ float s2[8][64];
    __shared__ float sfreq[40];
    __shared__ float sc[24];
    const int t = threadIdx.x;

    #pragma unroll
    for (int p = 0; p < 4; ++p) {
        const int idx = t + 512 * p;
        if (idx < 1920) ((float4*)shb)[idx] = ((const float4*)hb)[idx];
    }
    ((float4*)sw1)[t]       = ((const float4*)w1)[t];
    ((float4*)sw1)[t + 512] = ((const float4*)w1)[t + 512];
    ((float4*)sw2)[t]       = ((const float4*)w2)[t];
    ((float4*)sw2)[t + 512] = ((const float4*)w2)[t + 512];
    if (t < 48) ((float4*)swo)[t] = ((const float4*)wo)[t];
    if (t < 40) sfreq[t] = __expf((float)t * LN1024_OVER_39);
    if (t < 24) sc[t] = coord[t];
    __syncthreads();

    const int b = t >> 6, c = t & 63;

    // z1[b][c] = z1acc + sum_f z[b,f] * hb[f*64+c]
    float a = z1acc[t];
    #pragma unroll
    for (int i = 0; i < 3; ++i) {
        const float cv = sc[b * 3 + i];
        #pragma unroll 8
        for (int q = 0; q < 40; ++q)
            a += cv * sfreq[q] * shb[(i * 40 + q) * 64 + c];
    }
    sz[b][c] = a;  // no activation on modulated layer 0
    __syncthreads();

    float a1 = b1[c];
    #pragma unroll 8
    for (int cc = 0; cc < 64; ++cc) a1 += sz[b][cc] * sw1[cc * 64 + c];
    s2[b][c] = fmaxf(a1, 0.f);
    __syncthreads();

    float a2 = b2[c];
    #pragma unroll 8
    for (int cc = 0; cc < 64; ++cc) a2 += s2[b][cc] * sw2[cc * 64 + c];
    sz[b][c] = fmaxf(a2, 0.f);
    __syncthreads();

    if (t < 24) {
        const int bb = t / 3, i = t - bb * 3;
        float o = bo[i];
        #pragma unroll 8
        for (int cc = 0; cc < 64; ++cc) o += sz[bb][cc] * swo[cc * 3 + i];
        out[t] = o;
    }
}

// ---------------------------------------------------------------------------
extern "C" void kernel_launch(void* const* d_in, const int* in_sizes, int n_in,
                              void* d_out, int out_size, void* d_ws, size_t ws_size,
                              hipStream_t stream)
{
    const float* coord = (const float*)d_in[0];
    const float* feat0 = (const float*)d_in[1];
    const float* cw1 = (const float*)d_in[2];
    const float* cb1 = (const float*)d_in[3];
    const float* cw2 = (const float*)d_in[4];
    const float* cb2 = (const float*)d_in[5];
    const float* cw3 = (const float*)d_in[6];
    const float* cb3 = (const float*)d_in[7];
    const float* hw  = (const float*)d_in[8];
    const float* hb  = (const float*)d_in[9];
    const float* w1  = (const float*)d_in[10];
    const float* b1  = (const float*)d_in[11];
    const float* w2  = (const float*)d_in[12];
    const float* b2  = (const float*)d_in[13];
    const float* wo  = (const float*)d_in[14];
    const float* bo  = (const float*)d_in[15];
    float* out = (float*)d_out;

    float* fvecT   = (float*)d_ws;                  // 30720*8 floats = 983 KB
    float* partial = fvecT + (size_t)KTOT * 8;      // 3600*512 floats = 7.37 MB
    float* z1      = partial + (size_t)NBLK * 512;  // 512 floats

    k1_conv<<<dim3(8, 8, 8), 512, 0, stream>>>(feat0, cw1, cb1, cw2, cb2,
                                               cw3, cb3, fvecT);
    k2_stream<<<dim3(15, KSPLIT), 64, 0, stream>>>(hw, fvecT, coord, partial);
    k2b_reduce<<<64, 256, 0, stream>>>(partial, z1);
    k3_tail<<<1, 512, 0, stream>>>(z1, coord, hb, w1, b1, w2, b2, wo, bo, out);
}